// Round 14
// baseline (55.064 us; speedup 1.0000x reference)
//
#include <hip/hip_runtime.h>
#include <hip/hip_bf16.h>
#include <math.h>

// MRL-E loss, B=512, D=256, C=1000.
// loss = (1/(B*D)) * sum_i [ sum_k LSE_k(i) - sum_j z[i,j]*W[y_i,j]*(D-j) ]
// R14 = R13's MFMA logit pipeline (3 mfma per 16-class-tile per 32-k block:
// masked-prefix D1a/D1b + lane-local running-base update Lb) with the
// class-sum done IN REGISTERS instead of a second MFMA: D1's C/D layout puts
// a step's 4 classes in one lane's 4 regs -> 3 adds; accumulate over the 8
// class-tiles; one shfl_xor(16/32) pair per 32-k block completes the
// 128-class wave sum. Removes the per-tile exp->cvt->pack->MFMA feedback
// chain (2 MFMA + 12 VALU per tile) that serialized R13.

#define MRLE_B 512
#define MRLE_D 256
#define MRLE_C 1000
#define LOG2E 1.4426950408889634f
#define LN2   0.6931471805599453f

#if __has_builtin(__builtin_amdgcn_exp2f)
#define EXP2(x) __builtin_amdgcn_exp2f(x)
#else
#define EXP2(x) __builtin_exp2f(x)
#endif

typedef _Float16 half8 __attribute__((ext_vector_type(8)));
typedef float    f32x4 __attribute__((ext_vector_type(4)));

#define MFMA __builtin_amdgcn_mfma_f32_16x16x32_f16

// ---- prep: Wh[c][slot] = f16(W[c][k(slot)] * log2e); c >= 1000 -> 0 -------
// Slot reorder so the main kernel's 8-f16 A fragment is one 16B load:
// slot d = kb*32 + g*8 + e  <->  k = kb*32 + g*4 + (e&3) + 16*(e>>2)
__global__ __launch_bounds__(256) void mrle_prep(
    const float* __restrict__ W, _Float16* __restrict__ Wh,
    float* __restrict__ out)
{
    const int c = blockIdx.x;     // 0..1023
    const int d = threadIdx.x;    // 0..255
    if (c == 0 && d == 0) out[0] = 0.f;   // stream-ordered init
    const int kb = d >> 5, r5 = d & 31, g = r5 >> 3, e = r5 & 7;
    const int k  = kb * 32 + g * 4 + (e & 3) + ((e >> 2) << 4);
    float v = 0.f;
    if (c < MRLE_C) v = W[c * MRLE_D + k] * LOG2E;
    Wh[(size_t)c * MRLE_D + d] = (_Float16)v;
}

// ---- main: one block per row; 8 waves x 8 class-tiles (128 classes) -------
__global__ __launch_bounds__(512, 4) void mrle_main(
    const float* __restrict__ z,        // [B, D]
    const int* __restrict__ labels,     // [B]
    const float* __restrict__ W,        // [C, D] (label term)
    const _Float16* __restrict__ Wh,    // [1024, 256] f16, *log2e, slot-ordered
    float* __restrict__ out)            // [1]
{
    __shared__ float Sw[8 * MRLE_D];    // per-wave per-step partial sums, 8 KB
    __shared__ float wred[8];

    const int i  = blockIdx.x;
    const int t  = threadIdx.x;
    const int wv = t >> 6;
    const int l  = t & 63;
    const int lg = l >> 4;      // lane group 0..3 (k-slot group / class sub-row)
    const int ln = l & 15;      // A row (class), B col (step), C/D col (step)

    const float* zrow = z + (size_t)i * MRLE_D;

    // wave wv owns classes [wv*128, wv*128+128): 8 tiles of 16
    const _Float16* Abase = Wh + ((size_t)(wv * 128 + ln)) * MRLE_D + lg * 8;

    f32x4 Lb[8];
#pragma unroll
    for (int c8 = 0; c8 < 8; ++c8) Lb[c8] = (f32x4){0.f, 0.f, 0.f, 0.f};

    const _Float16 H0 = (_Float16)0.f;

    // rolling 4-deep A prefetch over flat it = kb*8 + cti
    half8 abuf[4];
#pragma unroll
    for (int p = 0; p < 4; ++p)
        abuf[p] = *(const half8*)(Abase + (size_t)p * 4096);

#pragma unroll 1
    for (int kb = 0; kb < 8; ++kb) {
        // z values for this 32-k block: lane needs j = lg*4+0..3 and +16
        const float4 zlo = *(const float4*)&zrow[kb * 32 + lg * 4];
        const float4 zhi = *(const float4*)&zrow[kb * 32 + 16 + lg * 4];
        const _Float16 zl0 = (_Float16)zlo.x, zl1 = (_Float16)zlo.y,
                       zl2 = (_Float16)zlo.z, zl3 = (_Float16)zlo.w;
        const _Float16 zh0 = (_Float16)zhi.x, zh1 = (_Float16)zhi.y,
                       zh2 = (_Float16)zhi.z, zh3 = (_Float16)zhi.w;
        // triangular masks: j' = lg*4+e <= q (= ln); same mask for j'+16<=q+16
        const bool m0 = (lg * 4 + 0) <= ln, m1 = (lg * 4 + 1) <= ln,
                   m2 = (lg * 4 + 2) <= ln, m3 = (lg * 4 + 3) <= ln;
        const half8 Ba = {m0 ? zl0 : H0, m1 ? zl1 : H0, m2 ? zl2 : H0,
                          m3 ? zl3 : H0, H0, H0, H0, H0};
        const half8 Bb = {zl0, zl1, zl2, zl3,
                          m0 ? zh0 : H0, m1 ? zh1 : H0, m2 ? zh2 : H0,
                          m3 ? zh3 : H0};
        const half8 Bz = {zl0, zl1, zl2, zl3, zh0, zh1, zh2, zh3};

        float Sa = 0.f, Sb = 0.f;   // this lane's class-partial for steps
                                    // kb*32+ln and kb*32+16+ln

#pragma unroll
        for (int cti = 0; cti < 8; ++cti) {
            const half8 A = abuf[cti & 3];
            if (kb < 7 || cti < 4) {               // prefetch it+4
                const int itn = kb * 8 + cti + 4;
                abuf[cti & 3] = *(const half8*)(Abase +
                    (size_t)(itn & 7) * 4096 + (size_t)(itn >> 3) * 32);
            }

            const f32x4 d1a = MFMA(A, Ba, Lb[cti], 0, 0, 0);
            const f32x4 d1b = MFMA(A, Bb, Lb[cti], 0, 0, 0);
            Lb[cti] = MFMA(A, Bz, Lb[cti], 0, 0, 0);   // lane-local base update

            // class-sum in registers: lane's 4 regs = 4 classes of one step
            float ea = (EXP2(d1a[0]) + EXP2(d1a[1])) +
                       (EXP2(d1a[2]) + EXP2(d1a[3]));
            float eb = (EXP2(d1b[0]) + EXP2(d1b[1])) +
                       (EXP2(d1b[2]) + EXP2(d1b[3]));
            if (wv == 7 && cti >= 6) {   // pad classes (c >= 1000): exp2(0)=1
                const float m = (cti == 7 || lg >= 2) ? 0.f : 1.f;
                ea *= m; eb *= m;
            }
            Sa += ea;
            Sb += eb;
        }

        // cross-lane-group reduce: sum the 4 lg sub-rows per step column
        Sa += __shfl_xor(Sa, 16);
        Sa += __shfl_xor(Sa, 32);
        Sb += __shfl_xor(Sb, 16);
        Sb += __shfl_xor(Sb, 32);

        if (l < 16) {
            Sw[wv * MRLE_D + kb * 32 + l]      = Sa;
            Sw[wv * MRLE_D + kb * 32 + 16 + l] = Sb;
        }
    }

    __syncthreads();

    float v = 0.f;
    if (t < MRLE_D) {
        float S = 0.f;
#pragma unroll
        for (int wq = 0; wq < 8; ++wq) S += Sw[wq * MRLE_D + t];
        const float lse = LN2 * __log2f(S);
        const int y = labels[i];
        const float lab = zrow[t] * W[(size_t)y * MRLE_D + t] *
                          (float)(MRLE_D - t);
        v = lse - lab;
    }
#pragma unroll
    for (int d = 1; d < 64; d <<= 1) v += __shfl_xor(v, d);
    if (l == 0) wred[wv] = v;
    __syncthreads();
    if (t == 0) {
        float tot = 0.f;
#pragma unroll
        for (int wq = 0; wq < 8; ++wq) tot += wred[wq];
        atomicAdd(out, tot * (1.0f / ((float)MRLE_B * (float)MRLE_D)));
    }
}

extern "C" void kernel_launch(void* const* d_in, const int* in_sizes, int n_in,
                              void* d_out, int out_size, void* d_ws, size_t ws_size,
                              hipStream_t stream) {
    const float* z      = (const float*)d_in[0];   // [512, 256]
    const int*   labels = (const int*)d_in[1];     // [512]
    const float* W      = (const float*)d_in[2];   // [1000, 256]
    float*       out    = (float*)d_out;           // scalar

    _Float16* Wh = (_Float16*)d_ws;   // [1024][256] f16 = 512 KB

    mrle_prep<<<1024, 256, 0, stream>>>(W, Wh, out);
    mrle_main<<<MRLE_B, 512, 0, stream>>>(z, labels, W, Wh, out);
}

// Round 15
// 48.007 us; speedup vs baseline: 1.1470x; 1.1470x over previous
//
#include <hip/hip_runtime.h>
#include <hip/hip_bf16.h>
#include <math.h>

// MRL-E loss, B=512, D=256, C=1000.
// loss = (1/(B*D)) * sum_i [ sum_k LSE_k(i) - sum_j z[i,j]*W[y_i,j]*(D-j) ]
// R15 = R14 (MFMA logit pipeline + in-register class-sum) with the VGPR cap
// RELEASED: R14's __launch_bounds__(512,4) forced 64 VGPR and spilled the
// loop-carried state (Lb[8]+abuf[4]+frags ~90 regs) to scratch — 13.3 MB/
// dispatch of scratch writes (vs 16 KB in R13) was the whole regression.
// __launch_bounds__(512) alone lets the allocator take ~128 VGPR: still
// 2 blocks/CU (4 waves/SIMD), zero spill.

#define MRLE_B 512
#define MRLE_D 256
#define MRLE_C 1000
#define LOG2E 1.4426950408889634f
#define LN2   0.6931471805599453f

#if __has_builtin(__builtin_amdgcn_exp2f)
#define EXP2(x) __builtin_amdgcn_exp2f(x)
#else
#define EXP2(x) __builtin_exp2f(x)
#endif

typedef _Float16 half8 __attribute__((ext_vector_type(8)));
typedef float    f32x4 __attribute__((ext_vector_type(4)));

#define MFMA __builtin_amdgcn_mfma_f32_16x16x32_f16

// ---- prep: Wh[c][slot] = f16(W[c][k(slot)] * log2e); c >= 1000 -> 0 -------
// Slot reorder so the main kernel's 8-f16 A fragment is one 16B load:
// slot d = kb*32 + g*8 + e  <->  k = kb*32 + g*4 + (e&3) + 16*(e>>2)
__global__ __launch_bounds__(256) void mrle_prep(
    const float* __restrict__ W, _Float16* __restrict__ Wh,
    float* __restrict__ out)
{
    const int c = blockIdx.x;     // 0..1023
    const int d = threadIdx.x;    // 0..255
    if (c == 0 && d == 0) out[0] = 0.f;   // stream-ordered init
    const int kb = d >> 5, r5 = d & 31, g = r5 >> 3, e = r5 & 7;
    const int k  = kb * 32 + g * 4 + (e & 3) + ((e >> 2) << 4);
    float v = 0.f;
    if (c < MRLE_C) v = W[c * MRLE_D + k] * LOG2E;
    Wh[(size_t)c * MRLE_D + d] = (_Float16)v;
}

// ---- main: one block per row; 8 waves x 8 class-tiles (128 classes) -------
__global__ __launch_bounds__(512) void mrle_main(
    const float* __restrict__ z,        // [B, D]
    const int* __restrict__ labels,     // [B]
    const float* __restrict__ W,        // [C, D] (label term)
    const _Float16* __restrict__ Wh,    // [1024, 256] f16, *log2e, slot-ordered
    float* __restrict__ out)            // [1]
{
    __shared__ float Sw[8 * MRLE_D];    // per-wave per-step partial sums, 8 KB
    __shared__ float wred[8];

    const int i  = blockIdx.x;
    const int t  = threadIdx.x;
    const int wv = t >> 6;
    const int l  = t & 63;
    const int lg = l >> 4;      // lane group 0..3 (k-slot group / class sub-row)
    const int ln = l & 15;      // A row (class), B col (step), C/D col (step)

    const float* zrow = z + (size_t)i * MRLE_D;

    // wave wv owns classes [wv*128, wv*128+128): 8 tiles of 16
    const _Float16* Abase = Wh + ((size_t)(wv * 128 + ln)) * MRLE_D + lg * 8;

    f32x4 Lb[8];
#pragma unroll
    for (int c8 = 0; c8 < 8; ++c8) Lb[c8] = (f32x4){0.f, 0.f, 0.f, 0.f};

    const _Float16 H0 = (_Float16)0.f;

    // rolling 4-deep A prefetch over flat it = kb*8 + cti
    half8 abuf[4];
#pragma unroll
    for (int p = 0; p < 4; ++p)
        abuf[p] = *(const half8*)(Abase + (size_t)p * 4096);

#pragma unroll 1
    for (int kb = 0; kb < 8; ++kb) {
        // z values for this 32-k block: lane needs j = lg*4+0..3 and +16
        const float4 zlo = *(const float4*)&zrow[kb * 32 + lg * 4];
        const float4 zhi = *(const float4*)&zrow[kb * 32 + 16 + lg * 4];
        const _Float16 zl0 = (_Float16)zlo.x, zl1 = (_Float16)zlo.y,
                       zl2 = (_Float16)zlo.z, zl3 = (_Float16)zlo.w;
        const _Float16 zh0 = (_Float16)zhi.x, zh1 = (_Float16)zhi.y,
                       zh2 = (_Float16)zhi.z, zh3 = (_Float16)zhi.w;
        // triangular masks: j' = lg*4+e <= q (= ln); same mask for j'+16<=q+16
        const bool m0 = (lg * 4 + 0) <= ln, m1 = (lg * 4 + 1) <= ln,
                   m2 = (lg * 4 + 2) <= ln, m3 = (lg * 4 + 3) <= ln;
        const half8 Ba = {m0 ? zl0 : H0, m1 ? zl1 : H0, m2 ? zl2 : H0,
                          m3 ? zl3 : H0, H0, H0, H0, H0};
        const half8 Bb = {zl0, zl1, zl2, zl3,
                          m0 ? zh0 : H0, m1 ? zh1 : H0, m2 ? zh2 : H0,
                          m3 ? zh3 : H0};
        const half8 Bz = {zl0, zl1, zl2, zl3, zh0, zh1, zh2, zh3};

        float Sa = 0.f, Sb = 0.f;   // this lane's class-partial for steps
                                    // kb*32+ln and kb*32+16+ln

#pragma unroll
        for (int cti = 0; cti < 8; ++cti) {
            const half8 A = abuf[cti & 3];
            if (kb < 7 || cti < 4) {               // prefetch it+4
                const int itn = kb * 8 + cti + 4;
                abuf[cti & 3] = *(const half8*)(Abase +
                    (size_t)(itn & 7) * 4096 + (size_t)(itn >> 3) * 32);
            }

            const f32x4 d1a = MFMA(A, Ba, Lb[cti], 0, 0, 0);
            const f32x4 d1b = MFMA(A, Bb, Lb[cti], 0, 0, 0);
            Lb[cti] = MFMA(A, Bz, Lb[cti], 0, 0, 0);   // lane-local base update

            // class-sum in registers: lane's 4 regs = 4 classes of one step
            float ea = (EXP2(d1a[0]) + EXP2(d1a[1])) +
                       (EXP2(d1a[2]) + EXP2(d1a[3]));
            float eb = (EXP2(d1b[0]) + EXP2(d1b[1])) +
                       (EXP2(d1b[2]) + EXP2(d1b[3]));
            if (wv == 7 && cti >= 6) {   // pad classes (c >= 1000): exp2(0)=1
                const float m = (cti == 7 || lg >= 2) ? 0.f : 1.f;
                ea *= m; eb *= m;
            }
            Sa += ea;
            Sb += eb;
        }

        // cross-lane-group reduce: sum the 4 lg sub-rows per step column
        Sa += __shfl_xor(Sa, 16);
        Sa += __shfl_xor(Sa, 32);
        Sb += __shfl_xor(Sb, 16);
        Sb += __shfl_xor(Sb, 32);

        if (l < 16) {
            Sw[wv * MRLE_D + kb * 32 + l]      = Sa;
            Sw[wv * MRLE_D + kb * 32 + 16 + l] = Sb;
        }
    }

    __syncthreads();

    float v = 0.f;
    if (t < MRLE_D) {
        float S = 0.f;
#pragma unroll
        for (int wq = 0; wq < 8; ++wq) S += Sw[wq * MRLE_D + t];
        const float lse = LN2 * __log2f(S);
        const int y = labels[i];
        const float lab = zrow[t] * W[(size_t)y * MRLE_D + t] *
                          (float)(MRLE_D - t);
        v = lse - lab;
    }
#pragma unroll
    for (int d = 1; d < 64; d <<= 1) v += __shfl_xor(v, d);
    if (l == 0) wred[wv] = v;
    __syncthreads();
    if (t == 0) {
        float tot = 0.f;
#pragma unroll
        for (int wq = 0; wq < 8; ++wq) tot += wred[wq];
        atomicAdd(out, tot * (1.0f / ((float)MRLE_B * (float)MRLE_D)));
    }
}

extern "C" void kernel_launch(void* const* d_in, const int* in_sizes, int n_in,
                              void* d_out, int out_size, void* d_ws, size_t ws_size,
                              hipStream_t stream) {
    const float* z      = (const float*)d_in[0];   // [512, 256]
    const int*   labels = (const int*)d_in[1];     // [512]
    const float* W      = (const float*)d_in[2];   // [1000, 256]
    float*       out    = (float*)d_out;           // scalar

    _Float16* Wh = (_Float16*)d_ws;   // [1024][256] f16 = 512 KB

    mrle_prep<<<1024, 256, 0, stream>>>(W, Wh, out);
    mrle_main<<<MRLE_B, 512, 0, stream>>>(z, labels, W, Wh, out);
}

// Round 16
// 41.820 us; speedup vs baseline: 1.3167x; 1.1480x over previous
//
#include <hip/hip_runtime.h>
#include <hip/hip_bf16.h>
#include <math.h>

// MRL-E loss, B=512, D=256, C=1000.
// loss = (1/(B*D)) * sum_i [ sum_k LSE_k(i) - sum_j z[i,j]*W[y_i,j]*(D-j) ]
// No-max LSE (logit std <= 0.32); logits in log2 domain (Wtb = W^T * log2e,
// bf16) so exp is one v_exp_f32 and lse = ln2 * log2(S).
// R16 = R11's barrier-free pipelined loop (imm-offset DS, software-pipelined
// chunk reduce, 8-deep linear global prefetch) + k-half split: grid =
// (row, h) = 1024 blocks x 512 thr = 8192 waves = 100% chip occupancy
// (R11 capped at 50%). h=1 blocks replay k<128 as fma-only chunks (~20%
// extra issue, no exp/reduce). Discriminates stall-limited vs issue-limited.

#define MRLE_B 512
#define MRLE_D 256
#define MRLE_C 1000
#define MRLE_CP 1024            // padded classes
#define MRLE_KROWS 264          // D + prefetch depth (pad rows: dead data)
#define MRLE_NT 512
#define ROWD (MRLE_CP / 2)      // dwords per k-row = 512
#define RSTR 17                 // redw lane stride (floats)
#define LOG2E 1.4426950408889634f
#define LN2   0.6931471805599453f

#if __has_builtin(__builtin_amdgcn_exp2f)
#define EXP2(x) __builtin_amdgcn_exp2f(x)
#else
#define EXP2(x) __builtin_exp2f(x)
#endif

// ---- transpose + bf16: Wtb[k][c] = bf16(W[c][k] * log2e); pad c -> 0 ------
// Also zeroes the output scalar (replaces a separate memset dispatch).
__global__ __launch_bounds__(256) void mrle_transpose(
    const float* __restrict__ W, unsigned short* __restrict__ Wtb,
    float* __restrict__ out)
{
    __shared__ float tile[64][65];
    const int c0 = blockIdx.x * 64;
    const int k0 = blockIdx.y * 64;
    const int t  = threadIdx.x;
    const int r  = t >> 2;
    const int q  = t & 3;

    if (c0 == 0 && k0 == 0 && t == 0) out[0] = 0.f;   // stream-ordered init

#pragma unroll
    for (int j = 0; j < 4; ++j) {
        const int c    = c0 + r;
        const int kcol = q * 4 + j * 16;
        float4 v = make_float4(0.f, 0.f, 0.f, 0.f);
        if (c < MRLE_C) v = *(const float4*)&W[(size_t)c * MRLE_D + k0 + kcol];
        tile[r][kcol + 0] = v.x;
        tile[r][kcol + 1] = v.y;
        tile[r][kcol + 2] = v.z;
        tile[r][kcol + 3] = v.w;
    }
    __syncthreads();

#pragma unroll
    for (int j = 0; j < 4; ++j) {
        const int cc = q * 4 + j * 16;
        unsigned short hh[4];
#pragma unroll
        for (int e = 0; e < 4; ++e) {
            const float f = tile[cc + e][r] * LOG2E;
            unsigned int u = __float_as_uint(f);
            u = (u + 0x7FFFu + ((u >> 16) & 1u)) >> 16;   // RNE to bf16
            hh[e] = (unsigned short)u;
        }
        *(ushort4*)&Wtb[(size_t)(k0 + r) * MRLE_CP + c0 + cc] =
            make_ushort4(hh[0], hh[1], hh[2], hh[3]);
    }
}

// ---- main: block = (row i, k-half h); 8 waves, 2 classes/thread -----------
__global__ __launch_bounds__(MRLE_NT) void mrle_main(
    const float* __restrict__ z,              // [B, D]
    const int* __restrict__ labels,           // [B]
    const float* __restrict__ W,              // [C, D] (label term)
    const unsigned short* __restrict__ Wtb,   // [KROWS, CP] bf16, *log2e
    float* __restrict__ out)                  // [1]
{
    __shared__ float zsh[MRLE_D];            // raw z row (1 KB)
    __shared__ float red[8 * 64 * RSTR];     // wave-private, 34 KB
    __shared__ float Sw[8 * 128];            // per-wave per-step partials, 4 KB
    __shared__ float wred[8];

    const int bid = blockIdx.x;
    const int i   = bid >> 1;
    const int h   = bid & 1;     // k-half: steps [h*128, h*128+128)
    const int t   = threadIdx.x;
    const int wv  = t >> 6;
    const int l   = t & 63;

    if (t < MRLE_D) zsh[t] = z[i * MRLE_D + t];
    __syncthreads();   // the only barrier before the tail

    // thread t owns classes 2t, 2t+1 (t >= 500 -> all pad, -inf logits)
    const int cbase = 2 * t;
    float l0 = (cbase     < MRLE_C) ? 0.f : -INFINITY;
    float l1 = (cbase + 1 < MRLE_C) ? 0.f : -INFINITY;

    const unsigned int* Wp = (const unsigned int*)Wtb + t;

    unsigned int wbuf[8];
#pragma unroll
    for (int q = 0; q < 8; ++q) wbuf[q] = Wp[(size_t)q * ROWD];

    // fixed per-lane LDS bases; all in-loop DS addresses are imm offsets
    float* redw = red + wv * (64 * RSTR);
    float* wr = redw + l * RSTR;                         // write base
    const float* rd = redw + (l & 48) * RSTR + (l & 15); // read base

    // h=1: replay k in [0,128) fma-only (no exp, no reduce), keep prefetch
    if (h) {
#pragma unroll 1
        for (int cb = 0; cb < 8; ++cb) {
            float zq[16];
            *(float4*)&zq[0]  = *(const float4*)&zsh[cb * 16 + 0];
            *(float4*)&zq[4]  = *(const float4*)&zsh[cb * 16 + 4];
            *(float4*)&zq[8]  = *(const float4*)&zsh[cb * 16 + 8];
            *(float4*)&zq[12] = *(const float4*)&zsh[cb * 16 + 12];
#pragma unroll
            for (int kk4 = 0; kk4 < 4; ++kk4) {
                const unsigned int* qp =
                    Wp + (size_t)(cb * 16 + kk4 * 4 + 10) * ROWD;
#pragma unroll
                for (int j = 0; j < 4; ++j) {
                    const int kk = kk4 * 4 + j;
                    const unsigned int w = wbuf[kk & 7];
                    const float w0 = __uint_as_float(w << 16);
                    const float w1 = __uint_as_float(w);
                    l0 = fmaf(zq[kk], w0, l0);
                    l1 = fmaf(zq[kk], w1, l1);
                    wbuf[kk & 7] = qp[(j - 2) * (int)ROWD];
                }
            }
        }
    }

    const int kst = h * 128;   // this block's exp-range start

#pragma unroll 1
    for (int cb = 0; cb < 8; ++cb) {
        // (A) software-pipelined reduce, part 1: issue chunk cb-1's reads
        // BEFORE this chunk's writes (in-order DS: reads beat overwrites)
        float r[16];
        if (cb > 0) {
#pragma unroll
            for (int u = 0; u < 16; ++u) r[u] = rd[u * RSTR];
        }

        float zq[16];
        *(float4*)&zq[0]  = *(const float4*)&zsh[kst + cb * 16 + 0];
        *(float4*)&zq[4]  = *(const float4*)&zsh[kst + cb * 16 + 4];
        *(float4*)&zq[8]  = *(const float4*)&zsh[kst + cb * 16 + 8];
        *(float4*)&zq[12] = *(const float4*)&zsh[kst + cb * 16 + 12];

        // (B) chunk compute: fma/exp/ds_write + 8-deep linear prefetch
#pragma unroll
        for (int kk4 = 0; kk4 < 4; ++kk4) {
            const unsigned int* qp =
                Wp + (size_t)(kst + cb * 16 + kk4 * 4 + 10) * ROWD;
#pragma unroll
            for (int j = 0; j < 4; ++j) {
                const int kk = kk4 * 4 + j;
                const unsigned int w = wbuf[kk & 7];
                const float w0 = __uint_as_float(w << 16);       // even class
                const float w1 = __uint_as_float(w);             // odd: bf16
                l0 = fmaf(zq[kk], w0, l0);   // + mantissa noise < bf16 quant
                l1 = fmaf(zq[kk], w1, l1);
                wr[kk] = EXP2(l0) + EXP2(l1);          // imm-offset ds_write
                wbuf[kk & 7] = qp[(j - 2) * (int)ROWD]; // imm-offset load
            }
        }

        // (C) pipelined reduce, part 2: finish chunk cb-1
        if (cb > 0) {
            float s = 0.f;
#pragma unroll
            for (int u = 0; u < 16; ++u) s += r[u];
            s += __shfl_xor(s, 16);
            s += __shfl_xor(s, 32);
            if (l < 16) Sw[wv * 128 + (cb - 1) * 16 + l] = s;
        }
    }

    // epilogue: reduce the last chunk (cb = 7)
    {
        float s = 0.f;
#pragma unroll
        for (int u = 0; u < 16; ++u) s += rd[u * RSTR];
        s += __shfl_xor(s, 16);
        s += __shfl_xor(s, 32);
        if (l < 16) Sw[wv * 128 + 7 * 16 + l] = s;
    }

    __syncthreads();   // combine the 8 waves' partials

    float v = 0.f;
    if (t < 128) {
        // thread t handles step k = kst + t
        float S = 0.f;
#pragma unroll
        for (int wq = 0; wq < 8; ++wq) S += Sw[wq * 128 + t];
        v = LN2 * __log2f(S);
    } else if (h == 0 && t < 128 + MRLE_D) {
        // telescoped label term (threads 128..383 handle feature j = t-128)
        const int j = t - 128;
        const int y = labels[i];
        v = -zsh[j] * W[(size_t)y * MRLE_D + j] * (float)(MRLE_D - j);
    }

#pragma unroll
    for (int d = 1; d < 64; d <<= 1) v += __shfl_xor(v, d);
    if (l == 0) wred[wv] = v;
    __syncthreads();
    if (t == 0) {
        float tot = 0.f;
#pragma unroll
        for (int wq = 0; wq < 8; ++wq) tot += wred[wq];
        atomicAdd(out, tot * (1.0f / ((float)MRLE_B * (float)MRLE_D)));
    }
}

extern "C" void kernel_launch(void* const* d_in, const int* in_sizes, int n_in,
                              void* d_out, int out_size, void* d_ws, size_t ws_size,
                              hipStream_t stream) {
    const float* z      = (const float*)d_in[0];   // [512, 256]
    const int*   labels = (const int*)d_in[1];     // [512]
    const float* W      = (const float*)d_in[2];   // [1000, 256]
    float*       out    = (float*)d_out;           // scalar

    // ws: Wtb [264][1024] bf16 = 528 KB; rows 256..263 prefetched, never used
    unsigned short* Wtb = (unsigned short*)d_ws;

    mrle_transpose<<<dim3(16, 4), 256, 0, stream>>>(W, Wtb, out);
    mrle_main<<<MRLE_B * 2, MRLE_NT, 0, stream>>>(z, labels, W, Wtb, out);
}